// Round 3
// baseline (3011.906 us; speedup 1.0000x reference)
//
#include <hip/hip_runtime.h>
#include <hip/hip_bf16.h>
#include <cstddef>

#define NHEADS 9
#define D 32
#define SQ 4096
#define RPAD 40              // LDS row stride in halfwords (80 B: 16B-aligned, 2-way banks max)
#define BUFHW (16 * RPAD)    // one P-buffer per wave, in halfwords

typedef __attribute__((ext_vector_type(8))) short bf16x8;
typedef __attribute__((ext_vector_type(4))) float f32x4;

__device__ __forceinline__ unsigned int f2bf(float f) {
    unsigned int u = __float_as_uint(f);
    u += 0x7fffu + ((u >> 16) & 1u);
    return u >> 16;
}

// ---------------------------------------------------------------------------
// Prep: bilinear upsample (32->64, half-pixel) + 1x1 convs -> Q,K,V (bf16) + t
// Q: [bh][n][d]  K: [bh][m][d]  V: [bh][d][m]
// ---------------------------------------------------------------------------
__global__ __launch_bounds__(256) void prep_kernel(
    const float* __restrict__ x2, const float* __restrict__ x1,
    const float* __restrict__ feat1,
    const float* __restrict__ Wq, const float* __restrict__ bq,
    const float* __restrict__ Wk, const float* __restrict__ bk,
    const float* __restrict__ Wv, const float* __restrict__ bv,
    const float* __restrict__ Wt, const float* __restrict__ bt,
    unsigned short* __restrict__ Qb, unsigned short* __restrict__ Kb,
    unsigned short* __restrict__ Vb, float* __restrict__ tbuf)
{
    int tid = blockIdx.x * blockDim.x + threadIdx.x;   // 0 .. 2*9*4096-1
    int n  = tid & (SQ - 1);
    int bh = tid >> 12;
    int h  = bh % NHEADS;
    int b  = bh / NHEADS;

    float xs0 = x2[((size_t)b * 3 + 0) * SQ + n];
    float xs1 = x2[((size_t)b * 3 + 1) * SQ + n];
    float xs2 = x2[((size_t)b * 3 + 2) * SQ + n];
    float ys0 = x1[((size_t)b * 3 + 0) * SQ + n];
    float ys1 = x1[((size_t)b * 3 + 1) * SQ + n];
    float ys2 = x1[((size_t)b * 3 + 2) * SQ + n];

    int yy = n >> 6, xx = n & 63;
    int jy = yy >> 1, jx = xx >> 1;
    int j0, j1, i0, i1; float wy0, wy1, wx0, wx1;
    if (yy & 1) { j0 = jy; j1 = (jy < 31) ? jy + 1 : 31; wy0 = 0.75f; wy1 = 0.25f; }
    else        { j0 = (jy > 0) ? jy - 1 : 0; j1 = jy;   wy0 = 0.25f; wy1 = 0.75f; }
    if (xx & 1) { i0 = jx; i1 = (jx < 31) ? jx + 1 : 31; wx0 = 0.75f; wx1 = 0.25f; }
    else        { i0 = (jx > 0) ? jx - 1 : 0; i1 = jx;   wx0 = 0.25f; wx1 = 0.75f; }

    float fu[4];
#pragma unroll
    for (int c = 0; c < 4; ++c) {
        const float* f = feat1 + ((size_t)b * 4 + c) * 1024;
        fu[c] = wy0 * (wx0 * f[j0 * 32 + i0] + wx1 * f[j0 * 32 + i1]) +
                wy1 * (wx0 * f[j1 * 32 + i0] + wx1 * f[j1 * 32 + i1]);
    }

    unsigned int qp[16], kp[16];
    float tacc = bt[0];
    int hd0 = h * D;
#pragma unroll
    for (int d = 0; d < D; ++d) {
        int hd = hd0 + d;
        float q = bq[hd] + Wq[hd * 3] * xs0 + Wq[hd * 3 + 1] * xs1 + Wq[hd * 3 + 2] * xs2;
        float k = bk[hd] + Wk[hd * 3] * ys0 + Wk[hd * 3 + 1] * ys1 + Wk[hd * 3 + 2] * ys2;
        float v = bv[hd] + Wv[hd * 4] * fu[0] + Wv[hd * 4 + 1] * fu[1] +
                  Wv[hd * 4 + 2] * fu[2] + Wv[hd * 4 + 3] * fu[3];
        tacc += q * Wt[d];
        unsigned int qb_ = f2bf(q), kb_ = f2bf(k);
        if (d & 1) { qp[d >> 1] |= qb_ << 16; kp[d >> 1] |= kb_ << 16; }
        else       { qp[d >> 1]  = qb_;       kp[d >> 1]  = kb_; }
        Vb[((size_t)bh * D + d) * SQ + n] = (unsigned short)f2bf(v);
    }
    tbuf[(size_t)bh * SQ + n] = tacc;

    uint4* qdst = (uint4*)(Qb + ((size_t)bh * SQ + n) * D);
    uint4* kdst = (uint4*)(Kb + ((size_t)bh * SQ + n) * D);
#pragma unroll
    for (int w = 0; w < 4; ++w) {
        qdst[w] = make_uint4(qp[4 * w], qp[4 * w + 1], qp[4 * w + 2], qp[4 * w + 3]);
        kdst[w] = make_uint4(kp[4 * w], kp[4 * w + 1], kp[4 * w + 2], kp[4 * w + 3]);
    }
}

// ---------------------------------------------------------------------------
// Attention: block = (b,h) x 64 query rows, 4 waves x 16 rows, full m-range.
// Software-pipelined: K/V double-buffered in registers (prefetch chunk it+1
// during iter it), P-tile skewed one iteration through 2 wave-private LDS
// buffers (write P(it) to buf[it&1], PV-consume P(it-1) from buf[~it&1]).
// ---------------------------------------------------------------------------
__global__ __launch_bounds__(256, 4) void attn_kernel(
    const unsigned short* __restrict__ Qb,
    const unsigned short* __restrict__ Kb,
    const unsigned short* __restrict__ Vb,
    const float* __restrict__ tbuf,
    const float* __restrict__ Wp,
    float* __restrict__ of)
{
    __shared__ __align__(16) unsigned short attn_s[4][2][BUFHW];  // [wave][buf][n*RPAD+m]
    __shared__ float of_s[4][64];

    const int bh   = blockIdx.y;
    const int h    = bh % NHEADS;
    const int b    = bh / NHEADS;
    const int n0   = blockIdx.x * 64;
    const int tid  = threadIdx.x;
    const int wave = tid >> 6;
    const int lane = tid & 63;
    const int l15  = lane & 15;
    const int quad = lane >> 4;

    of_s[tid >> 6][tid & 63] = 0.0f;
    __syncthreads();

    const int nw = n0 + wave * 16;

    bf16x8 a_q = *(const bf16x8*)(Qb + ((size_t)bh * SQ + nw + l15) * D + quad * 8);

    float tt[4];
#pragma unroll
    for (int r = 0; r < 4; ++r)
        tt[r] = tbuf[(size_t)bh * SQ + nw + quad * 4 + r] * (1.0f / 3000.0f);

    const float s1 = 5.892556509887896e-05f;   // 1/(sqrt(32)*3000)

    const unsigned short* kpp = Kb + (size_t)bh * SQ * D + l15 * D + quad * 8;
    const unsigned short* vpp = Vb + (size_t)bh * D * SQ + (size_t)l15 * SQ + quad * 8;

    f32x4 acc_lo = {0.f, 0.f, 0.f, 0.f};
    f32x4 acc_hi = {0.f, 0.f, 0.f, 0.f};
    unsigned short* as0 = &attn_s[wave][0][0];
    unsigned short* as1 = &attn_s[wave][1][0];

    // register double-buffers: slot c holds chunk with (chunk & 1) == c
    bf16x8 kA[2], kB[2], vL[2], vH[2];
    kA[0] = *(const bf16x8*)(kpp);
    kB[0] = *(const bf16x8*)(kpp + 16 * D);
    vL[0] = *(const bf16x8*)(vpp);
    vH[0] = *(const bf16x8*)(vpp + 16 * SQ);
    kA[1] = *(const bf16x8*)(kpp + 32 * D);
    kB[1] = *(const bf16x8*)(kpp + 48 * D);
    vL[1] = *(const bf16x8*)(vpp + 32);
    vH[1] = *(const bf16x8*)(vpp + 16 * SQ + 32);

    // prologue: QK(0) -> buf0
    {
        f32x4 z = {0.f, 0.f, 0.f, 0.f};
        f32x4 sa = __builtin_amdgcn_mfma_f32_16x16x32_bf16(a_q, kA[0], z, 0, 0, 0);
        f32x4 sb = __builtin_amdgcn_mfma_f32_16x16x32_bf16(a_q, kB[0], z, 0, 0, 0);
#pragma unroll
        for (int r = 0; r < 4; ++r) {
            float va = fmaxf(fmaf(sa[r], s1, -tt[r]), 0.0f);
            float vb = fmaxf(fmaf(sb[r], s1, -tt[r]), 0.0f);
            __hip_bfloat162 p = __float22bfloat162_rn(make_float2(va, vb));
            unsigned short* row = as0 + (quad * 4 + r) * RPAD;
            *(__hip_bfloat16*)(row + l15)      = p.x;
            *(__hip_bfloat16*)(row + 16 + l15) = p.y;
        }
    }

#pragma unroll 2
    for (int it = 1; it < 128; ++it) {
        const int cur = it & 1, prv = cur ^ 1;
        unsigned short* wcur = cur ? as1 : as0;
        unsigned short* wprv = cur ? as0 : as1;

        // QK(it) on prefetched K
        f32x4 z = {0.f, 0.f, 0.f, 0.f};
        f32x4 sa = __builtin_amdgcn_mfma_f32_16x16x32_bf16(a_q, kA[cur], z, 0, 0, 0);
        f32x4 sb = __builtin_amdgcn_mfma_f32_16x16x32_bf16(a_q, kB[cur], z, 0, 0, 0);

        // issue read of P(it-1) early; latency overlaps the relu/pack below
        bf16x8 a2 = *(const bf16x8*)(wprv + l15 * RPAD + quad * 8);

        // PV(it-1)
        acc_lo = __builtin_amdgcn_mfma_f32_16x16x32_bf16(a2, vL[prv], acc_lo, 0, 0, 0);
        acc_hi = __builtin_amdgcn_mfma_f32_16x16x32_bf16(a2, vH[prv], acc_hi, 0, 0, 0);

        // relu((sim-t)/3000) -> buf[cur]
#pragma unroll
        for (int r = 0; r < 4; ++r) {
            float va = fmaxf(fmaf(sa[r], s1, -tt[r]), 0.0f);
            float vb = fmaxf(fmaf(sb[r], s1, -tt[r]), 0.0f);
            __hip_bfloat162 p = __float22bfloat162_rn(make_float2(va, vb));
            unsigned short* row = wcur + (quad * 4 + r) * RPAD;
            *(__hip_bfloat16*)(row + l15)      = p.x;
            *(__hip_bfloat16*)(row + 16 + l15) = p.y;
        }

        // prefetch chunk it+1 into slot prv (reads past K/V end on it==127
        // land in adjacent workspace regions — harmless)
        const size_t ko = (size_t)(it + 1) * 32 * D;
        const size_t vo = (size_t)(it + 1) * 32;
        kA[prv] = *(const bf16x8*)(kpp + ko);
        kB[prv] = *(const bf16x8*)(kpp + ko + 16 * D);
        vL[prv] = *(const bf16x8*)(vpp + vo);
        vH[prv] = *(const bf16x8*)(vpp + vo + 16 * SQ);
    }

    // epilogue: PV(127) from buf1, V slot 1
    {
        bf16x8 a2 = *(const bf16x8*)(as1 + l15 * RPAD + quad * 8);
        acc_lo = __builtin_amdgcn_mfma_f32_16x16x32_bf16(a2, vL[1], acc_lo, 0, 0, 0);
        acc_hi = __builtin_amdgcn_mfma_f32_16x16x32_bf16(a2, vH[1], acc_hi, 0, 0, 0);
    }

    // out[n=quad*4+r][d=l15 (+16)] -> project with Wp[o][h*32+d]
    const int hd_lo = h * D + l15;
    const int hd_hi = hd_lo + 16;
#pragma unroll
    for (int r = 0; r < 4; ++r) {
        int nl = wave * 16 + quad * 4 + r;
#pragma unroll
        for (int o = 0; o < 4; ++o) {
            float c = acc_lo[r] * Wp[o * 288 + hd_lo] + acc_hi[r] * Wp[o * 288 + hd_hi];
            atomicAdd(&of_s[o][nl], c);
        }
    }
    __syncthreads();
    {
        int o = tid >> 6, nl = tid & 63;
        atomicAdd(&of[((size_t)b * 4 + o) * SQ + n0 + nl], of_s[o][nl]);
    }
}

// ---------------------------------------------------------------------------
// Final: 2x2-mean downsample + bias + residual; both tuple outputs.
// ---------------------------------------------------------------------------
__global__ void final_kernel(const float* __restrict__ of,
                             const float* __restrict__ sff,
                             const float* __restrict__ bp,
                             float* __restrict__ dout)
{
    int tid = blockIdx.x * blockDim.x + threadIdx.x;  // 0..8191
    if (tid >= 8192) return;
    int i  = tid & 31;
    int jj = (tid >> 5) & 31;
    int bo = tid >> 10;
    int o  = bo & 3;
    const float* src = of + (size_t)bo * SQ;
    int y = jj * 2, x = i * 2;
    float dval = 0.25f * (src[y * 64 + x] + src[y * 64 + x + 1] +
                          src[(y + 1) * 64 + x] + src[(y + 1) * 64 + x + 1]) + bp[o];
    dout[tid]        = sff[tid] + dval;
    dout[8192 + tid] = dval;
}

extern "C" void kernel_launch(void* const* d_in, const int* in_sizes, int n_in,
                              void* d_out, int out_size, void* d_ws, size_t ws_size,
                              hipStream_t stream)
{
    const float* second_frame = (const float*)d_in[0];
    const float* first_frame  = (const float*)d_in[1];
    const float* sff          = (const float*)d_in[2];
    const float* ffa          = (const float*)d_in[3];
    const float* Wq = (const float*)d_in[4];
    const float* bq = (const float*)d_in[5];
    const float* Wk = (const float*)d_in[6];
    const float* bk = (const float*)d_in[7];
    const float* Wv = (const float*)d_in[8];
    const float* bv = (const float*)d_in[9];
    const float* Wp = (const float*)d_in[10];
    const float* bp = (const float*)d_in[11];
    const float* Wt = (const float*)d_in[12];
    const float* bt = (const float*)d_in[13];
    float* out = (float*)d_out;

    char* ws = (char*)d_ws;
    const size_t QKV = (size_t)2 * NHEADS * SQ * D * sizeof(unsigned short);
    unsigned short* Qb = (unsigned short*)ws;
    unsigned short* Kb = (unsigned short*)(ws + QKV);
    unsigned short* Vb = (unsigned short*)(ws + 2 * QKV);
    float* tbuf = (float*)(ws + 3 * QKV);
    float* of   = (float*)(ws + 3 * QKV + (size_t)2 * NHEADS * SQ * sizeof(float));

    hipMemsetAsync(of, 0, (size_t)2 * 4 * SQ * sizeof(float), stream);
    prep_kernel<<<288, 256, 0, stream>>>(second_frame, first_frame, ffa,
                                         Wq, bq, Wk, bk, Wv, bv, Wt, bt,
                                         Qb, Kb, Vb, tbuf);
    dim3 ag(64, 18);
    attn_kernel<<<ag, 256, 0, stream>>>(Qb, Kb, Vb, tbuf, Wp, of);
    final_kernel<<<32, 256, 0, stream>>>(of, sff, bp, out);
}

// Round 4
// 446.263 us; speedup vs baseline: 6.7492x; 6.7492x over previous
//
#include <hip/hip_runtime.h>
#include <hip/hip_bf16.h>
#include <cstddef>

#define NHEADS 9
#define D 32
#define SQ 4096

typedef __attribute__((ext_vector_type(8))) short bf16x8;
typedef __attribute__((ext_vector_type(4))) short bf16x4;
typedef __attribute__((ext_vector_type(4))) float f32x4;

__device__ __forceinline__ unsigned int f2bf(float f) {
    unsigned int u = __float_as_uint(f);
    u += 0x7fffu + ((u >> 16) & 1u);
    return u >> 16;
}

// ---------------------------------------------------------------------------
// Prep: bilinear upsample (32->64, half-pixel) + 1x1 convs -> Q,K,V (bf16) + t
// Q: [bh][n][d]  K: [bh][m][d]  V: [bh][d][m]
// ---------------------------------------------------------------------------
__global__ __launch_bounds__(256) void prep_kernel(
    const float* __restrict__ x2, const float* __restrict__ x1,
    const float* __restrict__ feat1,
    const float* __restrict__ Wq, const float* __restrict__ bq,
    const float* __restrict__ Wk, const float* __restrict__ bk,
    const float* __restrict__ Wv, const float* __restrict__ bv,
    const float* __restrict__ Wt, const float* __restrict__ bt,
    unsigned short* __restrict__ Qb, unsigned short* __restrict__ Kb,
    unsigned short* __restrict__ Vb, float* __restrict__ tbuf)
{
    int tid = blockIdx.x * blockDim.x + threadIdx.x;   // 0 .. 2*9*4096-1
    int n  = tid & (SQ - 1);
    int bh = tid >> 12;
    int h  = bh % NHEADS;
    int b  = bh / NHEADS;

    float xs0 = x2[((size_t)b * 3 + 0) * SQ + n];
    float xs1 = x2[((size_t)b * 3 + 1) * SQ + n];
    float xs2 = x2[((size_t)b * 3 + 2) * SQ + n];
    float ys0 = x1[((size_t)b * 3 + 0) * SQ + n];
    float ys1 = x1[((size_t)b * 3 + 1) * SQ + n];
    float ys2 = x1[((size_t)b * 3 + 2) * SQ + n];

    int yy = n >> 6, xx = n & 63;
    int jy = yy >> 1, jx = xx >> 1;
    int j0, j1, i0, i1; float wy0, wy1, wx0, wx1;
    if (yy & 1) { j0 = jy; j1 = (jy < 31) ? jy + 1 : 31; wy0 = 0.75f; wy1 = 0.25f; }
    else        { j0 = (jy > 0) ? jy - 1 : 0; j1 = jy;   wy0 = 0.25f; wy1 = 0.75f; }
    if (xx & 1) { i0 = jx; i1 = (jx < 31) ? jx + 1 : 31; wx0 = 0.75f; wx1 = 0.25f; }
    else        { i0 = (jx > 0) ? jx - 1 : 0; i1 = jx;   wx0 = 0.25f; wx1 = 0.75f; }

    float fu[4];
#pragma unroll
    for (int c = 0; c < 4; ++c) {
        const float* f = feat1 + ((size_t)b * 4 + c) * 1024;
        fu[c] = wy0 * (wx0 * f[j0 * 32 + i0] + wx1 * f[j0 * 32 + i1]) +
                wy1 * (wx0 * f[j1 * 32 + i0] + wx1 * f[j1 * 32 + i1]);
    }

    unsigned int qp[16], kp[16];
    float tacc = bt[0];
    int hd0 = h * D;
#pragma unroll
    for (int d = 0; d < D; ++d) {
        int hd = hd0 + d;
        float q = bq[hd] + Wq[hd * 3] * xs0 + Wq[hd * 3 + 1] * xs1 + Wq[hd * 3 + 2] * xs2;
        float k = bk[hd] + Wk[hd * 3] * ys0 + Wk[hd * 3 + 1] * ys1 + Wk[hd * 3 + 2] * ys2;
        float v = bv[hd] + Wv[hd * 4] * fu[0] + Wv[hd * 4 + 1] * fu[1] +
                  Wv[hd * 4 + 2] * fu[2] + Wv[hd * 4 + 3] * fu[3];
        tacc += q * Wt[d];
        unsigned int qb_ = f2bf(q), kb_ = f2bf(k);
        if (d & 1) { qp[d >> 1] |= qb_ << 16; kp[d >> 1] |= kb_ << 16; }
        else       { qp[d >> 1]  = qb_;       kp[d >> 1]  = kb_; }
        Vb[((size_t)bh * D + d) * SQ + n] = (unsigned short)f2bf(v);
    }
    tbuf[(size_t)bh * SQ + n] = tacc;

    uint4* qdst = (uint4*)(Qb + ((size_t)bh * SQ + n) * D);
    uint4* kdst = (uint4*)(Kb + ((size_t)bh * SQ + n) * D);
#pragma unroll
    for (int w = 0; w < 4; ++w) {
        qdst[w] = make_uint4(qp[4 * w], qp[4 * w + 1], qp[4 * w + 2], qp[4 * w + 3]);
        kdst[w] = make_uint4(kp[4 * w], kp[4 * w + 1], kp[4 * w + 2], kp[4 * w + 3]);
    }
}

// ---------------------------------------------------------------------------
// Attention, transpose-free: per wave = one (b,h) x 16 query cols.
// QK: st = mfma_16x16x32(A=K_frag, B=Q_frag) -> S^T tile (row=m_local, col=n).
// S^T's C-layout (row = quad*4+r) IS the B-fragment layout of 16x16x16 MFMA
// (k = quad*4+i), so relu'd scores feed PV directly from registers:
//   out^T[d][n] += V[d][m] · P^T[m][n]  via mfma_f32_16x16x16bf16_1k.
// No LDS, no cross-lane, no barriers in the loop.
// ---------------------------------------------------------------------------
__global__ __launch_bounds__(256, 4) void attn_kernel(
    const unsigned short* __restrict__ Qb,
    const unsigned short* __restrict__ Kb,
    const unsigned short* __restrict__ Vb,
    const float* __restrict__ tbuf,
    const float* __restrict__ Wp,
    float* __restrict__ of)
{
    const int bh   = blockIdx.y;
    const int h    = bh % NHEADS;
    const int b    = bh / NHEADS;
    const int n0   = blockIdx.x * 64;
    const int tid  = threadIdx.x;
    const int wave = tid >> 6;
    const int lane = tid & 63;
    const int l15  = lane & 15;
    const int quad = lane >> 4;

    const int nw = n0 + wave * 16;

    // Q as B-fragment: B[d=quad*8+j][n=l15] = Q[nw+l15][quad*8+j]
    bf16x8 q_frag = *(const bf16x8*)(Qb + ((size_t)bh * SQ + nw + l15) * D + quad * 8);
    // per-lane threshold (depends only on n = l15)
    const float tt = tbuf[(size_t)bh * SQ + nw + l15] * (1.0f / 3000.0f);
    const float s1 = 5.892556509887896e-05f;   // 1/(sqrt(32)*3000)

    // K as A-fragment rows: A[m=l15][d=quad*8+j]
    const unsigned short* kp  = Kb + (size_t)bh * SQ * D + l15 * D + quad * 8;
    // V as A-fragment for PV: A[d=l15(+16)][k=quad*4+i] from V[d][m]
    const unsigned short* vlo = Vb + (size_t)bh * D * SQ + (size_t)l15 * SQ + quad * 4;
    const unsigned short* vhi = vlo + (size_t)16 * SQ;

    f32x4 acc_lo = {0.f, 0.f, 0.f, 0.f};
    f32x4 acc_hi = {0.f, 0.f, 0.f, 0.f};
    const f32x4 z = {0.f, 0.f, 0.f, 0.f};

#pragma unroll 4
    for (int mc = 0; mc < SQ; mc += 16) {
        bf16x8 kf = *(const bf16x8*)(kp + (size_t)mc * D);
        f32x4 st = __builtin_amdgcn_mfma_f32_16x16x32_bf16(kf, q_frag, z, 0, 0, 0);
        // P^T[m_local=quad*4+r][n=l15] = relu((st - t_n)/3000), packed to bf16x4
        float v0 = fmaxf(fmaf(st[0], s1, -tt), 0.0f);
        float v1 = fmaxf(fmaf(st[1], s1, -tt), 0.0f);
        float v2 = fmaxf(fmaf(st[2], s1, -tt), 0.0f);
        float v3 = fmaxf(fmaf(st[3], s1, -tt), 0.0f);
        union { __hip_bfloat162 h2[2]; bf16x4 v; } pu;
        pu.h2[0] = __float22bfloat162_rn(make_float2(v0, v1));
        pu.h2[1] = __float22bfloat162_rn(make_float2(v2, v3));
        bf16x4 pb = pu.v;
        bf16x4 va = *(const bf16x4*)(vlo + mc);
        bf16x4 vb = *(const bf16x4*)(vhi + mc);
        acc_lo = __builtin_amdgcn_mfma_f32_16x16x16bf16_1k(va, pb, acc_lo, 0, 0, 0);
        acc_hi = __builtin_amdgcn_mfma_f32_16x16x16bf16_1k(vb, pb, acc_hi, 0, 0, 0);
    }

    // lane holds out^T[d = quad*4+r (lo) / 16+quad*4+r (hi)][n = nw+l15].
    // Project 288->4 with Wp, reduce across quads, one atomic per (o,n).
    const float* wph = Wp + h * D + quad * 4;
#pragma unroll
    for (int o = 0; o < 4; ++o) {
        float c = 0.0f;
#pragma unroll
        for (int r = 0; r < 4; ++r)
            c += acc_lo[r] * wph[o * 288 + r] + acc_hi[r] * wph[o * 288 + 16 + r];
        c += __shfl_xor(c, 16);
        c += __shfl_xor(c, 32);
        if (quad == 0)
            atomicAdd(&of[((size_t)b * 4 + o) * SQ + nw + l15], c);
    }
}

// ---------------------------------------------------------------------------
// Final: 2x2-mean downsample + bias + residual; both tuple outputs.
// ---------------------------------------------------------------------------
__global__ void final_kernel(const float* __restrict__ of,
                             const float* __restrict__ sff,
                             const float* __restrict__ bp,
                             float* __restrict__ dout)
{
    int tid = blockIdx.x * blockDim.x + threadIdx.x;  // 0..8191
    if (tid >= 8192) return;
    int i  = tid & 31;
    int jj = (tid >> 5) & 31;
    int bo = tid >> 10;
    int o  = bo & 3;
    const float* src = of + (size_t)bo * SQ;
    int y = jj * 2, x = i * 2;
    float dval = 0.25f * (src[y * 64 + x] + src[y * 64 + x + 1] +
                          src[(y + 1) * 64 + x] + src[(y + 1) * 64 + x + 1]) + bp[o];
    dout[tid]        = sff[tid] + dval;
    dout[8192 + tid] = dval;
}

extern "C" void kernel_launch(void* const* d_in, const int* in_sizes, int n_in,
                              void* d_out, int out_size, void* d_ws, size_t ws_size,
                              hipStream_t stream)
{
    const float* second_frame = (const float*)d_in[0];
    const float* first_frame  = (const float*)d_in[1];
    const float* sff          = (const float*)d_in[2];
    const float* ffa          = (const float*)d_in[3];
    const float* Wq = (const float*)d_in[4];
    const float* bq = (const float*)d_in[5];
    const float* Wk = (const float*)d_in[6];
    const float* bk = (const float*)d_in[7];
    const float* Wv = (const float*)d_in[8];
    const float* bv = (const float*)d_in[9];
    const float* Wp = (const float*)d_in[10];
    const float* bp = (const float*)d_in[11];
    const float* Wt = (const float*)d_in[12];
    const float* bt = (const float*)d_in[13];
    float* out = (float*)d_out;

    char* ws = (char*)d_ws;
    const size_t QKV = (size_t)2 * NHEADS * SQ * D * sizeof(unsigned short);
    unsigned short* Qb = (unsigned short*)ws;
    unsigned short* Kb = (unsigned short*)(ws + QKV);
    unsigned short* Vb = (unsigned short*)(ws + 2 * QKV);
    float* tbuf = (float*)(ws + 3 * QKV);
    float* of   = (float*)(ws + 3 * QKV + (size_t)2 * NHEADS * SQ * sizeof(float));

    hipMemsetAsync(of, 0, (size_t)2 * 4 * SQ * sizeof(float), stream);
    prep_kernel<<<288, 256, 0, stream>>>(second_frame, first_frame, ffa,
                                         Wq, bq, Wk, bk, Wv, bv, Wt, bt,
                                         Qb, Kb, Vb, tbuf);
    dim3 ag(64, 18);
    attn_kernel<<<ag, 256, 0, stream>>>(Qb, Kb, Vb, tbuf, Wp, of);
    final_kernel<<<32, 256, 0, stream>>>(of, sff, bp, out);
}

// Round 5
// 415.272 us; speedup vs baseline: 7.2529x; 1.0746x over previous
//
#include <hip/hip_runtime.h>
#include <hip/hip_bf16.h>
#include <cstddef>

#define NHEADS 9
#define D 32
#define SQ 4096
#define ZSPLIT 4
#define MBLK (SQ / ZSPLIT)   // 1024 m per block
#define ITERS (MBLK / 16)    // 64

typedef __attribute__((ext_vector_type(8))) short bf16x8;
typedef __attribute__((ext_vector_type(4))) short bf16x4;
typedef __attribute__((ext_vector_type(4))) float f32x4;

__device__ __forceinline__ unsigned int f2bf(float f) {
    unsigned int u = __float_as_uint(f);
    u += 0x7fffu + ((u >> 16) & 1u);
    return u >> 16;
}

// ---------------------------------------------------------------------------
// Prep: bilinear upsample (32->64, half-pixel) + 1x1 convs -> Q,K,V (bf16) + t
// One thread per (bh, n, 8-d-group): 294912 threads (4x round-4 parallelism).
// Threshold t reduced over the 4-lane d-group via shfl_xor.
// Q: [bh][n][d]  K: [bh][m][d]  V: [bh][d][m]
// ---------------------------------------------------------------------------
__global__ __launch_bounds__(256) void prep_kernel(
    const float* __restrict__ x2, const float* __restrict__ x1,
    const float* __restrict__ feat1,
    const float* __restrict__ Wq, const float* __restrict__ bq,
    const float* __restrict__ Wk, const float* __restrict__ bk,
    const float* __restrict__ Wv, const float* __restrict__ bv,
    const float* __restrict__ Wt, const float* __restrict__ bt,
    unsigned short* __restrict__ Qb, unsigned short* __restrict__ Kb,
    unsigned short* __restrict__ Vb, float* __restrict__ tbuf)
{
    int idx = blockIdx.x * blockDim.x + threadIdx.x;   // 0 .. 2*9*4096*4-1
    int g  = idx & 3;                 // d-group: d = g*8 .. g*8+7
    int n  = (idx >> 2) & (SQ - 1);
    int bh = idx >> 14;               // 0..17
    int h  = bh % NHEADS;
    int b  = bh / NHEADS;

    float xs0 = x2[((size_t)b * 3 + 0) * SQ + n];
    float xs1 = x2[((size_t)b * 3 + 1) * SQ + n];
    float xs2 = x2[((size_t)b * 3 + 2) * SQ + n];
    float ys0 = x1[((size_t)b * 3 + 0) * SQ + n];
    float ys1 = x1[((size_t)b * 3 + 1) * SQ + n];
    float ys2 = x1[((size_t)b * 3 + 2) * SQ + n];

    // bilinear upsample coords: src = i*0.5 - 0.25 (half-pixel, align_corners=False)
    int yy = n >> 6, xx = n & 63;
    int jy = yy >> 1, jx = xx >> 1;
    int j0, j1, i0, i1; float wy0, wy1, wx0, wx1;
    if (yy & 1) { j0 = jy; j1 = (jy < 31) ? jy + 1 : 31; wy0 = 0.75f; wy1 = 0.25f; }
    else        { j0 = (jy > 0) ? jy - 1 : 0; j1 = jy;   wy0 = 0.25f; wy1 = 0.75f; }
    if (xx & 1) { i0 = jx; i1 = (jx < 31) ? jx + 1 : 31; wx0 = 0.75f; wx1 = 0.25f; }
    else        { i0 = (jx > 0) ? jx - 1 : 0; i1 = jx;   wx0 = 0.25f; wx1 = 0.75f; }

    float fu[4];
#pragma unroll
    for (int c = 0; c < 4; ++c) {
        const float* f = feat1 + ((size_t)b * 4 + c) * 1024;
        fu[c] = wy0 * (wx0 * f[j0 * 32 + i0] + wx1 * f[j0 * 32 + i1]) +
                wy1 * (wx0 * f[j1 * 32 + i0] + wx1 * f[j1 * 32 + i1]);
    }

    const int d0 = g * 8;
    unsigned int qp0, qp1, qp2, qp3, kp0, kp1, kp2, kp3;
    float tpart = 0.0f;
#pragma unroll
    for (int j = 0; j < 8; ++j) {
        int d = d0 + j, hd = h * D + d;
        float q = bq[hd] + Wq[hd * 3] * xs0 + Wq[hd * 3 + 1] * xs1 + Wq[hd * 3 + 2] * xs2;
        float k = bk[hd] + Wk[hd * 3] * ys0 + Wk[hd * 3 + 1] * ys1 + Wk[hd * 3 + 2] * ys2;
        float v = bv[hd] + Wv[hd * 4] * fu[0] + Wv[hd * 4 + 1] * fu[1] +
                  Wv[hd * 4 + 2] * fu[2] + Wv[hd * 4 + 3] * fu[3];
        tpart += q * Wt[d];
        unsigned int qb_ = f2bf(q), kb_ = f2bf(k);
        switch (j) {
            case 0: qp0 = qb_;        kp0 = kb_;        break;
            case 1: qp0 |= qb_ << 16; kp0 |= kb_ << 16; break;
            case 2: qp1 = qb_;        kp1 = kb_;        break;
            case 3: qp1 |= qb_ << 16; kp1 |= kb_ << 16; break;
            case 4: qp2 = qb_;        kp2 = kb_;        break;
            case 5: qp2 |= qb_ << 16; kp2 |= kb_ << 16; break;
            case 6: qp3 = qb_;        kp3 = kb_;        break;
            default:qp3 |= qb_ << 16; kp3 |= kb_ << 16; break;
        }
        Vb[((size_t)bh * D + d) * SQ + n] = (unsigned short)f2bf(v);
    }
    // reduce threshold partial over the 4-lane d-group (lanes 4k..4k+3)
    tpart += __shfl_xor(tpart, 1);
    tpart += __shfl_xor(tpart, 2);
    if (g == 0) tbuf[(size_t)bh * SQ + n] = tpart + bt[0];

    *(uint4*)(Qb + ((size_t)bh * SQ + n) * D + d0) = make_uint4(qp0, qp1, qp2, qp3);
    *(uint4*)(Kb + ((size_t)bh * SQ + n) * D + d0) = make_uint4(kp0, kp1, kp2, kp3);
}

// ---------------------------------------------------------------------------
// Attention, transpose-free + m-split + 1-deep prefetch.
// Per wave = one (b,h) x 16 query cols x 1024 m.
// QK: st = mfma_16x16x32(A=K_frag, B=Q_frag) -> S^T tile (row=m_local, col=n).
// S^T's C-layout IS the B-fragment layout of 16x16x16 MFMA, so relu'd scores
// feed PV directly from registers (no LDS/cross-lane/barrier in the loop).
// K/V prefetched one iteration ahead in NAMED registers (no arrays!).
// ---------------------------------------------------------------------------
__global__ __launch_bounds__(256, 8) void attn_kernel(
    const unsigned short* __restrict__ Qb,
    const unsigned short* __restrict__ Kb,
    const unsigned short* __restrict__ Vb,
    const float* __restrict__ tbuf,
    const float* __restrict__ Wp,
    float* __restrict__ of)
{
    const int bh   = blockIdx.y;
    const int h    = bh % NHEADS;
    const int b    = bh / NHEADS;
    const int n0   = blockIdx.x * 64;
    const int mc0  = blockIdx.z * MBLK;
    const int tid  = threadIdx.x;
    const int wave = tid >> 6;
    const int lane = tid & 63;
    const int l15  = lane & 15;
    const int quad = lane >> 4;

    const int nw = n0 + wave * 16;

    // Q as B-fragment: B[d=quad*8+j][n=l15]
    bf16x8 q_frag = *(const bf16x8*)(Qb + ((size_t)bh * SQ + nw + l15) * D + quad * 8);
    const float tt = tbuf[(size_t)bh * SQ + nw + l15] * (1.0f / 3000.0f);
    const float s1 = 5.892556509887896e-05f;   // 1/(sqrt(32)*3000)

    // K as A-fragment rows: A[m=l15][d=quad*8+j]
    const unsigned short* kp  = Kb + (size_t)bh * SQ * D + ((size_t)mc0 + l15) * D + quad * 8;
    // V as A-fragment for PV: A[d=l15(+16)][k=quad*4+i]
    const unsigned short* vlo = Vb + (size_t)bh * D * SQ + (size_t)l15 * SQ + mc0 + quad * 4;
    const unsigned short* vhi = vlo + (size_t)16 * SQ;

    f32x4 acc_lo = {0.f, 0.f, 0.f, 0.f};
    f32x4 acc_hi = {0.f, 0.f, 0.f, 0.f};
    const f32x4 z = {0.f, 0.f, 0.f, 0.f};

    bf16x8 kf = *(const bf16x8*)(kp);
    bf16x4 va = *(const bf16x4*)(vlo);
    bf16x4 vb = *(const bf16x4*)(vhi);

#pragma unroll 4
    for (int it = 0; it < ITERS; ++it) {
        // prefetch next chunk (final iteration reads 16 m past this block's
        // range; stays inside the workspace — value never consumed)
        bf16x8 kf_n = *(const bf16x8*)(kp + (size_t)(it + 1) * 16 * D);
        bf16x4 va_n = *(const bf16x4*)(vlo + (it + 1) * 16);
        bf16x4 vb_n = *(const bf16x4*)(vhi + (it + 1) * 16);

        f32x4 st = __builtin_amdgcn_mfma_f32_16x16x32_bf16(kf, q_frag, z, 0, 0, 0);
        // P^T[m_local=quad*4+r][n=l15] = relu((st - t_n)/3000) -> bf16x4
        float v0 = fmaxf(fmaf(st[0], s1, -tt), 0.0f);
        float v1 = fmaxf(fmaf(st[1], s1, -tt), 0.0f);
        float v2 = fmaxf(fmaf(st[2], s1, -tt), 0.0f);
        float v3 = fmaxf(fmaf(st[3], s1, -tt), 0.0f);
        union { __hip_bfloat162 h2[2]; bf16x4 v; } pu;
        pu.h2[0] = __float22bfloat162_rn(make_float2(v0, v1));
        pu.h2[1] = __float22bfloat162_rn(make_float2(v2, v3));
        bf16x4 pb = pu.v;
        acc_lo = __builtin_amdgcn_mfma_f32_16x16x16bf16_1k(va, pb, acc_lo, 0, 0, 0);
        acc_hi = __builtin_amdgcn_mfma_f32_16x16x16bf16_1k(vb, pb, acc_hi, 0, 0, 0);

        kf = kf_n; va = va_n; vb = vb_n;
    }

    // lane holds out^T[d = quad*4+r (lo) / 16+quad*4+r (hi)][n = nw+l15].
    // Project 288->4 with Wp, reduce across quads, one atomic per (o,n).
    const float* wph = Wp + h * D + quad * 4;
#pragma unroll
    for (int o = 0; o < 4; ++o) {
        float c = 0.0f;
#pragma unroll
        for (int r = 0; r < 4; ++r)
            c += acc_lo[r] * wph[o * 288 + r] + acc_hi[r] * wph[o * 288 + 16 + r];
        c += __shfl_xor(c, 16);
        c += __shfl_xor(c, 32);
        if (quad == 0)
            atomicAdd(&of[((size_t)b * 4 + o) * SQ + nw + l15], c);
    }
}

// ---------------------------------------------------------------------------
// Final: 2x2-mean downsample + bias + residual; both tuple outputs.
// ---------------------------------------------------------------------------
__global__ void final_kernel(const float* __restrict__ of,
                             const float* __restrict__ sff,
                             const float* __restrict__ bp,
                             float* __restrict__ dout)
{
    int tid = blockIdx.x * blockDim.x + threadIdx.x;  // 0..8191
    if (tid >= 8192) return;
    int i  = tid & 31;
    int jj = (tid >> 5) & 31;
    int bo = tid >> 10;
    int o  = bo & 3;
    const float* src = of + (size_t)bo * SQ;
    int y = jj * 2, x = i * 2;
    float dval = 0.25f * (src[y * 64 + x] + src[y * 64 + x + 1] +
                          src[(y + 1) * 64 + x] + src[(y + 1) * 64 + x + 1]) + bp[o];
    dout[tid]        = sff[tid] + dval;
    dout[8192 + tid] = dval;
}

extern "C" void kernel_launch(void* const* d_in, const int* in_sizes, int n_in,
                              void* d_out, int out_size, void* d_ws, size_t ws_size,
                              hipStream_t stream)
{
    const float* second_frame = (const float*)d_in[0];
    const float* first_frame  = (const float*)d_in[1];
    const float* sff          = (const float*)d_in[2];
    const float* ffa          = (const float*)d_in[3];
    const float* Wq = (const float*)d_in[4];
    const float* bq = (const float*)d_in[5];
    const float* Wk = (const float*)d_in[6];
    const float* bk = (const float*)d_in[7];
    const float* Wv = (const float*)d_in[8];
    const float* bv = (const float*)d_in[9];
    const float* Wp = (const float*)d_in[10];
    const float* bp = (const float*)d_in[11];
    const float* Wt = (const float*)d_in[12];
    const float* bt = (const float*)d_in[13];
    float* out = (float*)d_out;

    char* ws = (char*)d_ws;
    const size_t QKV = (size_t)2 * NHEADS * SQ * D * sizeof(unsigned short);
    unsigned short* Qb = (unsigned short*)ws;
    unsigned short* Kb = (unsigned short*)(ws + QKV);
    unsigned short* Vb = (unsigned short*)(ws + 2 * QKV);
    float* tbuf = (float*)(ws + 3 * QKV);
    float* of   = (float*)(ws + 3 * QKV + (size_t)2 * NHEADS * SQ * sizeof(float));

    hipMemsetAsync(of, 0, (size_t)2 * 4 * SQ * sizeof(float), stream);
    prep_kernel<<<1152, 256, 0, stream>>>(second_frame, first_frame, ffa,
                                          Wq, bq, Wk, bk, Wv, bv, Wt, bt,
                                          Qb, Kb, Vb, tbuf);
    dim3 ag(64, 18, ZSPLIT);
    attn_kernel<<<ag, 256, 0, stream>>>(Qb, Kb, Vb, tbuf, Wp, of);
    final_kernel<<<32, 256, 0, stream>>>(of, sff, bp, out);
}

// Round 6
// 149.602 us; speedup vs baseline: 20.1327x; 2.7758x over previous
//
#include <hip/hip_runtime.h>
#include <hip/hip_bf16.h>
#include <cstddef>

#define NHEADS 9
#define D 32
#define SQ 4096
#define ZSPLIT 4
#define MBLK (SQ / ZSPLIT)     // 1024 m per block
#define CHUNKS (MBLK / 64)     // 16 chunks of 64 m
#define KROW 40                // K LDS row stride (halfwords): 80 B
#define VROW 68                // V LDS row stride (halfwords): 136 B

typedef __attribute__((ext_vector_type(8))) short bf16x8;
typedef __attribute__((ext_vector_type(4))) short bf16x4;
typedef __attribute__((ext_vector_type(4))) float f32x4;

__device__ __forceinline__ unsigned int f2bf(float f) {
    unsigned int u = __float_as_uint(f);
    u += 0x7fffu + ((u >> 16) & 1u);
    return u >> 16;
}

// ---------------------------------------------------------------------------
// Prep: bilinear upsample (32->64, half-pixel) + 1x1 convs -> Q,K,V (bf16) + t
// One thread per (bh, n, 8-d-group). ALL stores are contiguous uint4:
// Q: [bh][n][d]   K: [bh][m][d]   V: [bh][m][d]   (d contiguous everywhere)
// ---------------------------------------------------------------------------
__global__ __launch_bounds__(256) void prep_kernel(
    const float* __restrict__ x2, const float* __restrict__ x1,
    const float* __restrict__ feat1,
    const float* __restrict__ Wq, const float* __restrict__ bq,
    const float* __restrict__ Wk, const float* __restrict__ bk,
    const float* __restrict__ Wv, const float* __restrict__ bv,
    const float* __restrict__ Wt, const float* __restrict__ bt,
    unsigned short* __restrict__ Qb, unsigned short* __restrict__ Kb,
    unsigned short* __restrict__ Vb, float* __restrict__ tbuf)
{
    int idx = blockIdx.x * blockDim.x + threadIdx.x;   // 0 .. 2*9*4096*4-1
    int g  = idx & 3;                 // d-group: d = g*8 .. g*8+7
    int n  = (idx >> 2) & (SQ - 1);
    int bh = idx >> 14;               // 0..17
    int h  = bh % NHEADS;
    int b  = bh / NHEADS;

    float xs0 = x2[((size_t)b * 3 + 0) * SQ + n];
    float xs1 = x2[((size_t)b * 3 + 1) * SQ + n];
    float xs2 = x2[((size_t)b * 3 + 2) * SQ + n];
    float ys0 = x1[((size_t)b * 3 + 0) * SQ + n];
    float ys1 = x1[((size_t)b * 3 + 1) * SQ + n];
    float ys2 = x1[((size_t)b * 3 + 2) * SQ + n];

    // bilinear upsample coords: src = i*0.5 - 0.25 (half-pixel, align_corners=False)
    int yy = n >> 6, xx = n & 63;
    int jy = yy >> 1, jx = xx >> 1;
    int j0, j1, i0, i1; float wy0, wy1, wx0, wx1;
    if (yy & 1) { j0 = jy; j1 = (jy < 31) ? jy + 1 : 31; wy0 = 0.75f; wy1 = 0.25f; }
    else        { j0 = (jy > 0) ? jy - 1 : 0; j1 = jy;   wy0 = 0.25f; wy1 = 0.75f; }
    if (xx & 1) { i0 = jx; i1 = (jx < 31) ? jx + 1 : 31; wx0 = 0.75f; wx1 = 0.25f; }
    else        { i0 = (jx > 0) ? jx - 1 : 0; i1 = jx;   wx0 = 0.25f; wx1 = 0.75f; }

    float fu[4];
#pragma unroll
    for (int c = 0; c < 4; ++c) {
        const float* f = feat1 + ((size_t)b * 4 + c) * 1024;
        fu[c] = wy0 * (wx0 * f[j0 * 32 + i0] + wx1 * f[j0 * 32 + i1]) +
                wy1 * (wx0 * f[j1 * 32 + i0] + wx1 * f[j1 * 32 + i1]);
    }

    const int d0 = g * 8;
    unsigned int qp[4], kp[4], vp[4];
    float tpart = 0.0f;
#pragma unroll
    for (int j = 0; j < 8; ++j) {
        int d = d0 + j, hd = h * D + d;
        float q = bq[hd] + Wq[hd * 3] * xs0 + Wq[hd * 3 + 1] * xs1 + Wq[hd * 3 + 2] * xs2;
        float k = bk[hd] + Wk[hd * 3] * ys0 + Wk[hd * 3 + 1] * ys1 + Wk[hd * 3 + 2] * ys2;
        float v = bv[hd] + Wv[hd * 4] * fu[0] + Wv[hd * 4 + 1] * fu[1] +
                  Wv[hd * 4 + 2] * fu[2] + Wv[hd * 4 + 3] * fu[3];
        tpart += q * Wt[d];
        unsigned int qb_ = f2bf(q), kb_ = f2bf(k), vb_ = f2bf(v);
        if (j & 1) { qp[j >> 1] |= qb_ << 16; kp[j >> 1] |= kb_ << 16; vp[j >> 1] |= vb_ << 16; }
        else       { qp[j >> 1]  = qb_;       kp[j >> 1]  = kb_;       vp[j >> 1]  = vb_; }
    }
    // reduce threshold partial over the 4-lane d-group
    tpart += __shfl_xor(tpart, 1);
    tpart += __shfl_xor(tpart, 2);
    if (g == 0) tbuf[(size_t)bh * SQ + n] = tpart + bt[0];

    size_t base = ((size_t)bh * SQ + n) * D + d0;
    *(uint4*)(Qb + base) = make_uint4(qp[0], qp[1], qp[2], qp[3]);
    *(uint4*)(Kb + base) = make_uint4(kp[0], kp[1], kp[2], kp[3]);
    *(uint4*)(Vb + base) = make_uint4(vp[0], vp[1], vp[2], vp[3]);
}

// ---------------------------------------------------------------------------
// Attention with block-cooperative LDS staging.
// Block = (bh, 128 n, 1024 m). Per 64-m chunk: stage K[64m][32d] (4KB contig)
// and V[64m][32d] (4KB contig, transposed to LDS [d][m]) with one uint4
// load/thread each; register-prefetch next chunk during compute.
// Per wave (32 n): per 16-m sub-chunk, kf = ds_read_b128 from K tile,
// ST = mfma_16x16x32(K,Q) x2, relu in C-layout (== B-layout of 16x16x16),
// PV = mfma_16x16x16 x4 on V fragments ds_read_b64 from [d][m] tile.
// LDS pads: K rows 80 B, V rows 136 B -> <=2-way banks on all hot ops.
// ---------------------------------------------------------------------------
__global__ __launch_bounds__(256, 6) void attn_kernel(
    const unsigned short* __restrict__ Qb,
    const unsigned short* __restrict__ Kb,
    const unsigned short* __restrict__ Vb,
    const float* __restrict__ tbuf,
    const float* __restrict__ Wp,
    float* __restrict__ of)
{
    __shared__ __align__(16) unsigned short Ks[64 * KROW];  // [m][d], 5120 B
    __shared__ __align__(16) unsigned short Vs[32 * VROW];  // [d][m], 4352 B

    const int bh   = blockIdx.y;
    const int h    = bh % NHEADS;
    const int b    = bh / NHEADS;
    const int n0   = blockIdx.x * 128;
    const int mc0  = blockIdx.z * MBLK;
    const int tid  = threadIdx.x;
    const int wave = tid >> 6;
    const int lane = tid & 63;
    const int l15  = lane & 15;
    const int quad = lane >> 4;

    const int nw1 = n0 + wave * 32;
    const int nw2 = nw1 + 16;

    // Q as B-fragment: B[d=quad*8+j][n=l15]
    bf16x8 qf1 = *(const bf16x8*)(Qb + ((size_t)bh * SQ + nw1 + l15) * D + quad * 8);
    bf16x8 qf2 = *(const bf16x8*)(Qb + ((size_t)bh * SQ + nw2 + l15) * D + quad * 8);
    const float tt1 = tbuf[(size_t)bh * SQ + nw1 + l15] * (1.0f / 3000.0f);
    const float tt2 = tbuf[(size_t)bh * SQ + nw2 + l15] * (1.0f / 3000.0f);
    const float s1 = 5.892556509887896e-05f;   // 1/(sqrt(32)*3000)

    const uint4* Kg4 = (const uint4*)(Kb + (size_t)bh * SQ * D);
    const uint4* Vg4 = (const uint4*)(Vb + (size_t)bh * SQ * D);

    // staging addresses (per thread): 16B each of the 4KB chunk
    const int krow = tid >> 2;            // m row 0..63
    const int kcol = (tid & 3) * 8;       // halfword col in 32-d row
    unsigned short* kdst = Ks + krow * KROW + kcol;
    // V transpose scatter dst: d = kcol+j, m = krow
    unsigned short* vdst = Vs + kcol * VROW + krow;

    f32x4 acc1l = {0.f,0.f,0.f,0.f}, acc1h = {0.f,0.f,0.f,0.f};
    f32x4 acc2l = {0.f,0.f,0.f,0.f}, acc2h = {0.f,0.f,0.f,0.f};
    const f32x4 z = {0.f,0.f,0.f,0.f};

    uint4 kreg = Kg4[(size_t)mc0 * 4 + tid];
    uint4 vreg = Vg4[(size_t)mc0 * 4 + tid];

    for (int c = 0; c < CHUNKS; ++c) {
        __syncthreads();   // previous compute done; buffers free
        *(uint4*)kdst = kreg;
        {
            union { uint4 u; unsigned short s[8]; } vv; vv.u = vreg;
#pragma unroll
            for (int j = 0; j < 8; ++j) vdst[j * VROW] = vv.s[j];
        }
        // prefetch next chunk (last iter reads past this bh's K/V — stays
        // inside workspace, never consumed)
        kreg = Kg4[(size_t)(mc0 + (c + 1) * 64) * 4 + tid];
        vreg = Vg4[(size_t)(mc0 + (c + 1) * 64) * 4 + tid];
        __syncthreads();   // staged data visible

#pragma unroll
        for (int s = 0; s < 4; ++s) {
            bf16x8 kf = *(const bf16x8*)(Ks + (s * 16 + l15) * KROW + quad * 8);
            f32x4 st1 = __builtin_amdgcn_mfma_f32_16x16x32_bf16(kf, qf1, z, 0, 0, 0);
            f32x4 st2 = __builtin_amdgcn_mfma_f32_16x16x32_bf16(kf, qf2, z, 0, 0, 0);
            bf16x4 va = *(const bf16x4*)(Vs + l15 * VROW + s * 16 + quad * 4);
            bf16x4 vb = *(const bf16x4*)(Vs + (l15 + 16) * VROW + s * 16 + quad * 4);

            float a0 = fmaxf(fmaf(st1[0], s1, -tt1), 0.0f);
            float a1 = fmaxf(fmaf(st1[1], s1, -tt1), 0.0f);
            float a2 = fmaxf(fmaf(st1[2], s1, -tt1), 0.0f);
            float a3 = fmaxf(fmaf(st1[3], s1, -tt1), 0.0f);
            union { __hip_bfloat162 h2[2]; bf16x4 v; } p1;
            p1.h2[0] = __float22bfloat162_rn(make_float2(a0, a1));
            p1.h2[1] = __float22bfloat162_rn(make_float2(a2, a3));

            float b0 = fmaxf(fmaf(st2[0], s1, -tt2), 0.0f);
            float b1 = fmaxf(fmaf(st2[1], s1, -tt2), 0.0f);
            float b2 = fmaxf(fmaf(st2[2], s1, -tt2), 0.0f);
            float b3 = fmaxf(fmaf(st2[3], s1, -tt2), 0.0f);
            union { __hip_bfloat162 h2[2]; bf16x4 v; } p2;
            p2.h2[0] = __float22bfloat162_rn(make_float2(b0, b1));
            p2.h2[1] = __float22bfloat162_rn(make_float2(b2, b3));

            acc1l = __builtin_amdgcn_mfma_f32_16x16x16bf16_1k(va, p1.v, acc1l, 0, 0, 0);
            acc1h = __builtin_amdgcn_mfma_f32_16x16x16bf16_1k(vb, p1.v, acc1h, 0, 0, 0);
            acc2l = __builtin_amdgcn_mfma_f32_16x16x16bf16_1k(va, p2.v, acc2l, 0, 0, 0);
            acc2h = __builtin_amdgcn_mfma_f32_16x16x16bf16_1k(vb, p2.v, acc2h, 0, 0, 0);
        }
    }

    // lane holds out^T[d = quad*4+r (lo) / 16+... (hi)][n]. Project 288->4,
    // reduce across quads, one atomic per (o, n) from quad 0.
    const float* wph = Wp + h * D + quad * 4;
#pragma unroll
    for (int o = 0; o < 4; ++o) {
        float c1 = 0.0f, c2 = 0.0f;
#pragma unroll
        for (int r = 0; r < 4; ++r) {
            c1 += acc1l[r] * wph[o * 288 + r] + acc1h[r] * wph[o * 288 + 16 + r];
            c2 += acc2l[r] * wph[o * 288 + r] + acc2h[r] * wph[o * 288 + 16 + r];
        }
        c1 += __shfl_xor(c1, 16); c1 += __shfl_xor(c1, 32);
        c2 += __shfl_xor(c2, 16); c2 += __shfl_xor(c2, 32);
        if (quad == 0) {
            atomicAdd(&of[((size_t)b * 4 + o) * SQ + nw1 + l15], c1);
            atomicAdd(&of[((size_t)b * 4 + o) * SQ + nw2 + l15], c2);
        }
    }
}

// ---------------------------------------------------------------------------
// Final: 2x2-mean downsample + bias + residual; both tuple outputs.
// ---------------------------------------------------------------------------
__global__ void final_kernel(const float* __restrict__ of,
                             const float* __restrict__ sff,
                             const float* __restrict__ bp,
                             float* __restrict__ dout)
{
    int tid = blockIdx.x * blockDim.x + threadIdx.x;  // 0..8191
    if (tid >= 8192) return;
    int i  = tid & 31;
    int jj = (tid >> 5) & 31;
    int bo = tid >> 10;
    int o  = bo & 3;
    const float* src = of + (size_t)bo * SQ;
    int y = jj * 2, x = i * 2;
    float dval = 0.25f * (src[y * 64 + x] + src[y * 64 + x + 1] +
                          src[(y + 1) * 64 + x] + src[(y + 1) * 64 + x + 1]) + bp[o];
    dout[tid]        = sff[tid] + dval;
    dout[8192 + tid] = dval;
}

extern "C" void kernel_launch(void* const* d_in, const int* in_sizes, int n_in,
                              void* d_out, int out_size, void* d_ws, size_t ws_size,
                              hipStream_t stream)
{
    const float* second_frame = (const float*)d_in[0];
    const float* first_frame  = (const float*)d_in[1];
    const float* sff          = (const float*)d_in[2];
    const float* ffa          = (const float*)d_in[3];
    const float* Wq = (const float*)d_in[4];
    const float* bq = (const float*)d_in[5];
    const float* Wk = (const float*)d_in[6];
    const float* bk = (const float*)d_in[7];
    const float* Wv = (const float*)d_in[8];
    const float* bv = (const float*)d_in[9];
    const float* Wp = (const float*)d_in[10];
    const float* bp = (const float*)d_in[11];
    const float* Wt = (const float*)d_in[12];
    const float* bt = (const float*)d_in[13];
    float* out = (float*)d_out;

    char* ws = (char*)d_ws;
    const size_t QKV = (size_t)2 * NHEADS * SQ * D * sizeof(unsigned short);
    unsigned short* Qb = (unsigned short*)ws;
    unsigned short* Kb = (unsigned short*)(ws + QKV);
    unsigned short* Vb = (unsigned short*)(ws + 2 * QKV);
    float* tbuf = (float*)(ws + 3 * QKV);
    float* of   = (float*)(ws + 3 * QKV + (size_t)2 * NHEADS * SQ * sizeof(float));

    hipMemsetAsync(of, 0, (size_t)2 * 4 * SQ * sizeof(float), stream);
    prep_kernel<<<1152, 256, 0, stream>>>(second_frame, first_frame, ffa,
                                          Wq, bq, Wk, bk, Wv, bv, Wt, bt,
                                          Qb, Kb, Vb, tbuf);
    dim3 ag(32, 18, ZSPLIT);
    attn_kernel<<<ag, 256, 0, stream>>>(Qb, Kb, Vb, tbuf, Wp, of);
    final_kernel<<<32, 256, 0, stream>>>(of, sff, bp, out);
}